// Round 5
// baseline (231.229 us; speedup 1.0000x reference)
//
#include <hip/hip_runtime.h>

// PointPillarScatter3d on MI355X (gfx950)
// NZ=1, NY=NX=512, C=128, B=4, P=320000.
// Strategy: scatter->gather inversion.
//   hipMemsetAsync: map[B*CELLS] = -1
//   k_scatter_idx:  map[b*CELLS + cell] = point index (cells unique per batch)
//   k_gather:       128-cell tile per block, full 128 channels, 2 barriers total.
//     Phase B: 16 independent 512B row gathers/thread (float4 nontemporal),
//              scalar LDS writes into [128][129] (4-way conflict, non-critical pipe).
//     Phase C: 16 independent 512B-contiguous channel-chunk stores (nontemporal).
//              2-way LDS read aliasing = free.
//   Every stream is touch-once -> nontemporal load/store to bypass L2 allocation.
//   Full output covered -> zeros from LDS for empty cells, no separate zero pass.

#define NXD 512
#define NYD 512
#define NZD 1
#define CB  128
#define CELLS (NXD * NYD * NZD)   // 262144

#define TILE 128                  // cells per block

typedef float f4 __attribute__((ext_vector_type(4)));   // clang-native vec for nontemporal

__global__ void k_scatter_idx(const int* __restrict__ coords,
                              int* __restrict__ map, int P) {
    int p = blockIdx.x * blockDim.x + threadIdx.x;
    if (p >= P) return;
    int4 c = ((const int4*)coords)[p];      // (b, z, y, x)
    int cell = c.y * (NYD * NXD) + c.z * NXD + c.w;
    map[c.x * CELLS + cell] = p;
}

__global__ __launch_bounds__(256) void k_gather(const float* __restrict__ feat,
                                                const int* __restrict__ map,
                                                float* __restrict__ out) {
    __shared__ int   pidx[TILE];
    __shared__ float tile[TILE][CB + 1];    // 66,048 B; +1 pad -> phase-C 2-way (free)

    const int t = threadIdx.x;
    const int tiles_per_b = CELLS / TILE;   // 2048
    const int b = blockIdx.x / tiles_per_b;
    const int cell_base = (blockIdx.x % tiles_per_b) * TILE;

    if (t < TILE) pidx[t] = map[b * CELLS + cell_base + t];
    __syncthreads();

    // Phase B: gather rows. 32 lanes x float4 = one 512B row; 8 rows in flight,
    // 16 passes -> 128 rows. All 16 loads independent (idx hoisted first).
    {
        const int c4 = t & 31;     // float4 column within row
        const int r0 = t >> 5;     // 0..7
        int idxr[16];
        #pragma unroll
        for (int rr = 0; rr < 16; ++rr) idxr[rr] = pidx[rr * 8 + r0];
        #pragma unroll
        for (int rr = 0; rr < 16; ++rr) {
            const int x = rr * 8 + r0;
            f4 v = (f4)(0.f);
            if (idxr[rr] >= 0)
                v = __builtin_nontemporal_load(
                        (const f4*)feat + (size_t)idxr[rr] * (CB / 4) + c4);
            tile[x][c4 * 4 + 0] = v.x;
            tile[x][c4 * 4 + 1] = v.y;
            tile[x][c4 * 4 + 2] = v.z;
            tile[x][c4 * 4 + 3] = v.w;
        }
    }
    __syncthreads();

    // Phase C: per channel, 32 lanes x float4 = 512B contiguous store.
    // 2 channels per wave instruction, 16 passes -> 128 channels.
    {
        const int x4 = t & 31;     // float4 index along 128 cells
        const int cr = t >> 5;     // 0..7
        float* outb = out + (size_t)b * CB * CELLS + cell_base;
        #pragma unroll
        for (int cc = 0; cc < 16; ++cc) {
            const int c = cc * 8 + cr;
            f4 v;
            v.x = tile[x4 * 4 + 0][c];
            v.y = tile[x4 * 4 + 1][c];
            v.z = tile[x4 * 4 + 2][c];
            v.w = tile[x4 * 4 + 3][c];
            __builtin_nontemporal_store(
                v, (f4*)(outb + (size_t)c * CELLS + x4 * 4));
        }
    }
}

extern "C" void kernel_launch(void* const* d_in, const int* in_sizes, int n_in,
                              void* d_out, int out_size, void* d_ws, size_t ws_size,
                              hipStream_t stream) {
    const float* feat   = (const float*)d_in[1];
    const int*   coords = (const int*)d_in[2];
    float*       out    = (float*)d_out;
    int*         map    = (int*)d_ws;   // B*CELLS int32 = 4 MB

    const int B = out_size / (CB * CELLS);
    const int P = in_sizes[1] / CB;
    const int n_map = B * CELLS;

    (void)hipMemsetAsync(map, 0xFF, (size_t)n_map * sizeof(int), stream);
    k_scatter_idx<<<(P + 255) / 256, 256, 0, stream>>>(coords, map, P);
    k_gather<<<B * (CELLS / TILE), 256, 0, stream>>>(feat, map, out);
}

// Round 6
// 191.101 us; speedup vs baseline: 1.2100x; 1.2100x over previous
//
#include <hip/hip_runtime.h>

// PointPillarScatter3d on MI355X (gfx950)
// NZ=1, NY=NX=512, C=128, B=4, P=320000.
// Strategy: scatter->gather inversion.
//   hipMemsetAsync: map[B*CELLS] = -1
//   k_scatter_idx:  map[b*CELLS + cell] = point index (cells unique per batch)
//   k_gather:       128-cell tile per block, 512 threads, 2 barriers.
//     Phase B: 8 independent 512B full-row gathers/thread (regular float4 loads),
//              scalar LDS writes, 4-way bank aliasing (cheap, hidden under HBM latency).
//     Phase C: one conflict-free ds_read_b128 per channel-chunk, then 512B-contiguous
//              float4 stores (regular stores -> L2 write-coalescing intact).
//   LDS: f4 ldsC[128ch][32 x-slots], slot swizzle x4 ^ (c4&7):
//     - phase C read (fixed c, lanes span x4): permutation of 32 slots -> conflict-free b128
//     - phase B write (fixed x, lanes span c):  banks 4*((x4^(c4&7))&7)+xe -> 8 banks, 4-way
//   Full output covered -> zeros from LDS for empty cells, no separate zero pass.

#define NXD 512
#define NYD 512
#define NZD 1
#define CB  128
#define CELLS (NXD * NYD * NZD)   // 262144

#define TILE 128                  // cells per block
#define NTHR 512                  // 8 waves; 2 blocks/CU (64KB LDS) = 16 waves/CU

typedef float f4 __attribute__((ext_vector_type(4)));

__global__ void k_scatter_idx(const int* __restrict__ coords,
                              int* __restrict__ map, int P) {
    int p = blockIdx.x * blockDim.x + threadIdx.x;
    if (p >= P) return;
    int4 c = ((const int4*)coords)[p];      // (b, z, y, x)
    int cell = c.y * (NYD * NXD) + c.z * NXD + c.w;
    map[c.x * CELLS + cell] = p;
}

__global__ __launch_bounds__(NTHR) void k_gather(const float* __restrict__ feat,
                                                 const int* __restrict__ map,
                                                 float* __restrict__ out) {
    __shared__ int pidx[TILE];
    __shared__ f4  ldsC[CB][TILE / 4];      // [channel][x-slot], swizzled; 64 KB

    const int t = threadIdx.x;
    const int tiles_per_b = CELLS / TILE;   // 2048
    const int b = blockIdx.x / tiles_per_b;
    const int cell_base = (blockIdx.x % tiles_per_b) * TILE;

    if (t < TILE) pidx[t] = map[b * CELLS + cell_base + t];
    __syncthreads();

    // Phase B: 32 lanes x float4 = one 512B row; 16 rows in flight, 8 passes.
    {
        const int c4 = t & 31;     // float4 column within row (channels 4c4..4c4+3)
        const int r0 = t >> 5;     // 0..15
        int idxr[8];
        #pragma unroll
        for (int rr = 0; rr < 8; ++rr) idxr[rr] = pidx[rr * 16 + r0];
        #pragma unroll
        for (int rr = 0; rr < 8; ++rr) {
            const int x = rr * 16 + r0;
            f4 v = (f4)(0.f);
            if (idxr[rr] >= 0)
                v = ((const f4*)feat)[(size_t)idxr[rr] * (CB / 4) + c4];
            const int slot = (x >> 2) ^ (c4 & 7);
            const int xe   = x & 3;
            ((float*)&ldsC[c4 * 4 + 0][slot])[xe] = v.x;
            ((float*)&ldsC[c4 * 4 + 1][slot])[xe] = v.y;
            ((float*)&ldsC[c4 * 4 + 2][slot])[xe] = v.z;
            ((float*)&ldsC[c4 * 4 + 3][slot])[xe] = v.w;
        }
    }
    __syncthreads();

    // Phase C: per channel, one conflict-free b128 read + 32 lanes x float4
    // = 512B contiguous store. 16 channels in flight, 8 passes.
    {
        const int x4 = t & 31;     // float4 index along 128 cells
        const int cr = t >> 5;     // 0..15
        float* outb = out + (size_t)b * CB * CELLS + cell_base;
        #pragma unroll
        for (int cc = 0; cc < 8; ++cc) {
            const int c = cc * 16 + cr;
            f4 v = ldsC[c][x4 ^ ((c >> 2) & 7)];
            *reinterpret_cast<f4*>(outb + (size_t)c * CELLS + x4 * 4) = v;
        }
    }
}

extern "C" void kernel_launch(void* const* d_in, const int* in_sizes, int n_in,
                              void* d_out, int out_size, void* d_ws, size_t ws_size,
                              hipStream_t stream) {
    const float* feat   = (const float*)d_in[1];
    const int*   coords = (const int*)d_in[2];
    float*       out    = (float*)d_out;
    int*         map    = (int*)d_ws;   // B*CELLS int32 = 4 MB

    const int B = out_size / (CB * CELLS);
    const int P = in_sizes[1] / CB;
    const int n_map = B * CELLS;

    (void)hipMemsetAsync(map, 0xFF, (size_t)n_map * sizeof(int), stream);
    k_scatter_idx<<<(P + 255) / 256, 256, 0, stream>>>(coords, map, P);
    k_gather<<<B * (CELLS / TILE), NTHR, 0, stream>>>(feat, map, out);
}